// Round 1
// baseline (95.074 us; speedup 1.0000x reference)
//
#include <hip/hip_runtime.h>
#include <math.h>

// LDDMM variational RHS, Gaussian kernel sigma=0.1, B=1, N=8192, D=3.
// out[0:N*3]     = dmom_i = (1/sig^2) * (x_i * sum_j W_ij - sum_j W_ij x_j)
// out[N*3:2*N*3] = dcp_i  = sum_j K_ij p_j
// K_ij = exp(-|x_i-x_j|^2/(2 sig^2)), W_ij = K_ij*(p_i.p_j), p=clamp(mom,-1,1)
//
// R7 theory: dur 89.7 = 43.3 (harness 268MB d_ws poison fill, fixed tax)
// + ~41 partial + ~3.5 reduce + overhead. Partial is 4x its VALU floor; two
// invariant causes across flat R3-R6: (a) 2x ds_read_b128 per 128 pairs =
// 1.05M wave LDS instrs * ~12cy = ~20us/CU on the shared LDS pipe; (b) v2f
// packing likely scalarized (R6 flat). Fix: pack along J (j-data read from
// LDS as natural 64b pairs; i-side splats hoisted out of the loop -> no
// per-iter splat), force VOP3P via inline asm, IPT=4 i's/thread so 4 reads
// serve 512 pairs (LDS instrs halved twice -> ~10us/CU). JC=128 keeps
// 1024 blocks. Predict partial ~13us, total ~64us.

#define NPTS 8192
#define N3   (NPTS * 3)
#define BI   256
#define IPT  4                        // i-points per thread
#define IBLK (NPTS / (BI * IPT))      // 8 i-blocks
#define JC   128                      // j-chunks
#define JLEN (NPTS / JC)              // 64 j's per chunk
#define NJP  (JLEN / 2)               // 32 j-pairs per chunk

// exp(-d2/(2*0.1^2)) = exp2(d2 * (-50*log2(e)))
#define COEF    (-72.134752044448170f)
#define M2COEF  (144.269504088896340f)     // -2*COEF
#define UNSC100 (0.69314718055994531f)     // 100 / M2COEF

#define WS_NEEDED ((size_t)JC * NPTS * 8 * sizeof(float))  // 33.55 MB

typedef float v2f __attribute__((ext_vector_type(2)));

__device__ __forceinline__ v2f vsplat(float s) { v2f r; r.x = s; r.y = s; return r; }

// Guaranteed VOP3P packed fp32 (gfx90a+). All operands are true 64-bit
// pairs -> clean "v" (VReg_64) constraints, default op_sel/op_sel_hi.
__device__ __forceinline__ v2f pk_fma(v2f a, v2f b, v2f c) {
    v2f d;
    asm("v_pk_fma_f32 %0, %1, %2, %3" : "=v"(d) : "v"(a), "v"(b), "v"(c));
    return d;
}
__device__ __forceinline__ v2f pk_add(v2f a, v2f b) {
    v2f d;
    asm("v_pk_add_f32 %0, %1, %2" : "=v"(d) : "v"(a), "v"(b));
    return d;
}
__device__ __forceinline__ v2f pk_mul(v2f a, v2f b) {
    v2f d;
    asm("v_pk_mul_f32 %0, %1, %2" : "=v"(d) : "v"(a), "v"(b));
    return d;
}

__device__ __forceinline__ float fast_exp2(float x) {
#if __has_builtin(__builtin_amdgcn_exp2f)
    return __builtin_amdgcn_exp2f(x);
#else
    return exp2f(x);
#endif
}

__device__ __forceinline__ float clamp1(float v) {
    return fminf(fmaxf(v, -1.0f), 1.0f);
}

// ws layout: ws[((c*NPTS)+i)*8 + k], k=0..3: dcp0,dcp1,dcp2,wsum
//                                    k=4..7: wxs0,wxs1,wxs2,0 (wxs = M2COEF*wx)
//
// LDS j-pair layout (per pair jp, 4 float4 = 64B):
//  [0] = {M2*x0(j0), M2*x0(j1), M2*x1(j0), M2*x1(j1)}
//  [1] = {M2*x2(j0), M2*x2(j1), cj(j0),    cj(j1)}      cj = COEF*|xj|^2
//  [2] = {p0(j0),    p0(j1),    p1(j0),    p1(j1)}
//  [3] = {p2(j0),    p2(j1),    0,         0}
__global__ __launch_bounds__(BI, 2) void lddmm_partial(const float* __restrict__ mom,
                                                       const float* __restrict__ cp,
                                                       float* __restrict__ ws) {
    const int ib = (int)blockIdx.x / JC;
    const int jc = (int)blockIdx.x % JC;
    const int t  = (int)threadIdx.x;

    __shared__ float4 shj[NJP][4];
    if (t < NJP) {
        const int j0 = jc * JLEN + 2 * t;
        const int j1 = j0 + 1;
        const float xa0 = cp[j0 * 3 + 0], xa1 = cp[j0 * 3 + 1], xa2 = cp[j0 * 3 + 2];
        const float xb0 = cp[j1 * 3 + 0], xb1 = cp[j1 * 3 + 1], xb2 = cp[j1 * 3 + 2];
        shj[t][0] = make_float4(M2COEF * xa0, M2COEF * xb0, M2COEF * xa1, M2COEF * xb1);
        shj[t][1] = make_float4(M2COEF * xa2, M2COEF * xb2,
                                COEF * (xa0 * xa0 + xa1 * xa1 + xa2 * xa2),
                                COEF * (xb0 * xb0 + xb1 * xb1 + xb2 * xb2));
        shj[t][2] = make_float4(clamp1(mom[j0 * 3 + 0]), clamp1(mom[j1 * 3 + 0]),
                                clamp1(mom[j0 * 3 + 1]), clamp1(mom[j1 * 3 + 1]));
        shj[t][3] = make_float4(clamp1(mom[j0 * 3 + 2]), clamp1(mom[j1 * 3 + 2]),
                                0.0f, 0.0f);
    }

    // i-side state: loop-invariant splats (hoisted; built once, cost ~0).
    v2f sx0[IPT], sx1[IPT], sx2[IPT], sci[IPT], sp0[IPT], sp1[IPT], sp2[IPT];
    const int ibase = ib * (BI * IPT) + t;
#pragma unroll
    for (int k = 0; k < IPT; ++k) {
        const int i = ibase + k * BI;
        const float x0 = cp[i * 3 + 0], x1 = cp[i * 3 + 1], x2 = cp[i * 3 + 2];
        sx0[k] = vsplat(x0);
        sx1[k] = vsplat(x1);
        sx2[k] = vsplat(x2);
        sci[k] = vsplat(COEF * (x0 * x0 + x1 * x1 + x2 * x2));
        sp0[k] = vsplat(clamp1(mom[i * 3 + 0]));
        sp1[k] = vsplat(clamp1(mom[i * 3 + 1]));
        sp2[k] = vsplat(clamp1(mom[i * 3 + 2]));
    }
    __syncthreads();

    v2f dcp0[IPT], dcp1[IPT], dcp2[IPT], wsum[IPT], wx0[IPT], wx1[IPT], wx2[IPT];
#pragma unroll
    for (int k = 0; k < IPT; ++k) {
        dcp0[k] = vsplat(0.f); dcp1[k] = vsplat(0.f); dcp2[k] = vsplat(0.f);
        wsum[k] = vsplat(0.f);
        wx0[k] = vsplat(0.f); wx1[k] = vsplat(0.f); wx2[k] = vsplat(0.f);
    }

    for (int jp = 0; jp < NJP; ++jp) {
        const float4 A = shj[jp][0];     // 4x ds_read_b128, wave-uniform bcast
        const float4 B = shj[jp][1];
        const float4 C = shj[jp][2];
        const float4 D = shj[jp][3];
        v2f xj0p; xj0p.x = A.x; xj0p.y = A.y;
        v2f xj1p; xj1p.x = A.z; xj1p.y = A.w;
        v2f xj2p; xj2p.x = B.x; xj2p.y = B.y;
        v2f cjp;  cjp.x  = B.z; cjp.y  = B.w;
        v2f pj0p; pj0p.x = C.x; pj0p.y = C.y;
        v2f pj1p; pj1p.x = C.z; pj1p.y = C.w;
        v2f pj2p; pj2p.x = D.x; pj2p.y = D.y;
#pragma unroll
        for (int k = 0; k < IPT; ++k) {
            // arg = ci + cj + xi . (M2*xj) = COEF*d2   (1 pk_add + 3 pk_fma)
            v2f arg = pk_add(sci[k], cjp);
            arg = pk_fma(sx0[k], xj0p, arg);
            arg = pk_fma(sx1[k], xj1p, arg);
            arg = pk_fma(sx2[k], xj2p, arg);
            v2f K;                             // 2 trans
            K.x = fast_exp2(arg.x);
            K.y = fast_exp2(arg.y);
            v2f pd = pk_mul(sp0[k], pj0p);     // 1 pk_mul + 2 pk_fma
            pd = pk_fma(sp1[k], pj1p, pd);
            pd = pk_fma(sp2[k], pj2p, pd);
            const v2f W = pk_mul(K, pd);       // 1 pk_mul
            dcp0[k] = pk_fma(K, pj0p, dcp0[k]); // 3 pk_fma
            dcp1[k] = pk_fma(K, pj1p, dcp1[k]);
            dcp2[k] = pk_fma(K, pj2p, dcp2[k]);
            wsum[k] = pk_add(wsum[k], W);       // 1 pk_add
            wx0[k] = pk_fma(W, xj0p, wx0[k]);   // 3 pk_fma (M2COEF-scaled)
            wx1[k] = pk_fma(W, xj1p, wx1[k]);
            wx2[k] = pk_fma(W, xj2p, wx2[k]);
        }
    }

#pragma unroll
    for (int k = 0; k < IPT; ++k) {
        const int i = ibase + k * BI;
        float4* o = (float4*)(ws + ((size_t)(jc * NPTS) + i) * 8);
        o[0] = make_float4(dcp0[k].x + dcp0[k].y, dcp1[k].x + dcp1[k].y,
                           dcp2[k].x + dcp2[k].y, wsum[k].x + wsum[k].y);
        o[1] = make_float4(wx0[k].x + wx0[k].y, wx1[k].x + wx1[k].y,
                           wx2[k].x + wx2[k].y, 0.0f);
    }
}

// 8 threads per i: sub = (cpart<<1)|half, cpart in 0..3 sums JC/4 chunks of
// one float4 slot; xor-2 and xor-4 combine cparts, xor-1 hands wsum to the
// wx half. dmom = 100*xi*wsum - (100/M2COEF)*wxs.
__global__ __launch_bounds__(256) void lddmm_reduce(const float* __restrict__ ws,
                                                    const float* __restrict__ cp,
                                                    float* __restrict__ out) {
    const int tid   = (int)blockIdx.x * 256 + (int)threadIdx.x;
    const int i     = tid >> 3;
    const int sub   = tid & 7;
    const int half  = sub & 1;
    const int cpart = sub >> 1;

    float4 acc = make_float4(0.f, 0.f, 0.f, 0.f);
    const int c0 = cpart * (JC / 4);
#pragma unroll 4
    for (int c = c0; c < c0 + JC / 4; ++c) {
        const float4 v = ((const float4*)(ws + ((size_t)(c * NPTS) + i) * 8))[half];
        acc.x += v.x; acc.y += v.y; acc.z += v.z; acc.w += v.w;
    }
    acc.x += __shfl_xor(acc.x, 2);
    acc.y += __shfl_xor(acc.y, 2);
    acc.z += __shfl_xor(acc.z, 2);
    acc.w += __shfl_xor(acc.w, 2);
    acc.x += __shfl_xor(acc.x, 4);
    acc.y += __shfl_xor(acc.y, 4);
    acc.z += __shfl_xor(acc.z, 4);
    acc.w += __shfl_xor(acc.w, 4);
    const float wsum = __shfl_xor(acc.w, 1);
    if (sub == 0) {
        out[N3 + i * 3 + 0] = acc.x;
        out[N3 + i * 3 + 1] = acc.y;
        out[N3 + i * 3 + 2] = acc.z;
    } else if (sub == 1) {
        const float xi0 = cp[i * 3 + 0];
        const float xi1 = cp[i * 3 + 1];
        const float xi2 = cp[i * 3 + 2];
        out[i * 3 + 0] = fmaf(100.0f * xi0, wsum, -UNSC100 * acc.x);
        out[i * 3 + 1] = fmaf(100.0f * xi1, wsum, -UNSC100 * acc.y);
        out[i * 3 + 2] = fmaf(100.0f * xi2, wsum, -UNSC100 * acc.z);
    }
}

// ---- fallback (atomics into d_out) if ws_size < WS_NEEDED ----
#define FJC   32
#define FJLEN (NPTS / FJC)
__global__ __launch_bounds__(BI) void lddmm_pairs_atomic(const float* __restrict__ mom,
                                                         const float* __restrict__ cp,
                                                         float* __restrict__ out) {
    const int ib = (int)blockIdx.x / FJC;
    const int jc = (int)blockIdx.x % FJC;
    const int t  = (int)threadIdx.x;
    const int i  = ib * BI + t;

    const float xi0 = cp[i * 3 + 0], xi1 = cp[i * 3 + 1], xi2 = cp[i * 3 + 2];
    const float pi0 = clamp1(mom[i * 3 + 0]), pi1 = clamp1(mom[i * 3 + 1]),
                pi2 = clamp1(mom[i * 3 + 2]);

    __shared__ float4 shx[FJLEN];
    __shared__ float4 shp[FJLEN];
    {
        const int j = jc * FJLEN + t;
        shx[t] = make_float4(cp[j * 3 + 0], cp[j * 3 + 1], cp[j * 3 + 2], 0.0f);
        shp[t] = make_float4(clamp1(mom[j * 3 + 0]), clamp1(mom[j * 3 + 1]),
                             clamp1(mom[j * 3 + 2]), 0.0f);
    }
    __syncthreads();

    float dcp0 = 0.f, dcp1 = 0.f, dcp2 = 0.f, wsum = 0.f, wx0 = 0.f, wx1 = 0.f, wx2 = 0.f;
#pragma unroll 4
    for (int jj = 0; jj < FJLEN; ++jj) {
        const float4 xj = shx[jj];
        const float4 pj = shp[jj];
        const float dx0 = xi0 - xj.x, dx1 = xi1 - xj.y, dx2 = xi2 - xj.z;
        const float d2  = dx0 * dx0 + dx1 * dx1 + dx2 * dx2;
        const float K   = fast_exp2(d2 * COEF);
        const float pd  = pi0 * pj.x + pi1 * pj.y + pi2 * pj.z;
        const float W   = K * pd;
        dcp0 += K * pj.x; dcp1 += K * pj.y; dcp2 += K * pj.z;
        wsum += W;
        wx0 += W * xj.x; wx1 += W * xj.y; wx2 += W * xj.z;
    }
    atomicAdd(&out[i * 3 + 0], 100.0f * (xi0 * wsum - wx0));
    atomicAdd(&out[i * 3 + 1], 100.0f * (xi1 * wsum - wx1));
    atomicAdd(&out[i * 3 + 2], 100.0f * (xi2 * wsum - wx2));
    atomicAdd(&out[N3 + i * 3 + 0], dcp0);
    atomicAdd(&out[N3 + i * 3 + 1], dcp1);
    atomicAdd(&out[N3 + i * 3 + 2], dcp2);
}

extern "C" void kernel_launch(void* const* d_in, const int* in_sizes, int n_in,
                              void* d_out, int out_size, void* d_ws, size_t ws_size,
                              hipStream_t stream) {
    const float* mom = (const float*)d_in[0];
    const float* cp  = (const float*)d_in[1];
    float* out = (float*)d_out;

    if (ws_size >= WS_NEEDED) {
        float* ws = (float*)d_ws;
        hipLaunchKernelGGL(lddmm_partial, dim3(IBLK * JC), dim3(BI), 0, stream, mom, cp, ws);
        hipLaunchKernelGGL(lddmm_reduce, dim3(NPTS * 8 / 256), dim3(256), 0, stream, ws, cp, out);
    } else {
        hipMemsetAsync(out, 0, (size_t)out_size * sizeof(float), stream);
        hipLaunchKernelGGL(lddmm_pairs_atomic, dim3((NPTS / BI) * FJC), dim3(BI), 0, stream, mom, cp, out);
    }
}

// Round 6
// 90.293 us; speedup vs baseline: 1.0529x; 1.0529x over previous
//
#include <hip/hip_runtime.h>
#include <math.h>

// LDDMM variational RHS, Gaussian kernel sigma=0.1, B=1, N=8192, D=3.
// out[0:N*3]     = dmom_i = (1/sig^2) * (x_i * sum_j W_ij - sum_j W_ij x_j)
// out[N*3:2*N*3] = dcp_i  = sum_j K_ij p_j
// K_ij = exp(-|x_i-x_j|^2/(2 sig^2)), W_ij = K_ij*(p_i.p_j), p=clamp(mom,-1,1)
//
// R12: BYTE-EXACT control resubmission of the Round-0 kernel (best verified:
// 89.4us prev session, 89.7us Round 0). Rationale: R8-R11 all failed, and
// R11 was a verified-correct re-parameterization of the passing R7 envelope
// (plain dispatches + ws staging + plain stores) -- no kernel-side mechanism
// remains for its failure. Control discriminates environment flakiness from
// content bugs. If this passes ~89-95us: every in-envelope lever measured
// flat (inner loop, LDS traffic, ws size, packing, fusion) and all envelope
// escapes fail the replay harness -> dur = optimal 268MB poison fill
// (~43-50us @ 6.2TB/s) + ~46us structural replay/drain residual = roofline.
// If this fails: harness state is the variable; no kernel is evaluable.

#define NPTS 8192
#define N3   (NPTS * 3)
#define BI   256
#define IBLK (NPTS / (BI * 2))       // 16 i-blocks (2 i's per thread, packed)
#define JC   64
#define JLEN (NPTS / JC)             // 128 j's per chunk

// exp(-d2/(2*0.1^2)) = exp2(d2 * (-50*log2(e)))
#define COEF    (-72.134752044448170f)
#define M2COEF  (144.269504088896340f)     // -2*COEF
#define UNSC100 (0.69314718055994531f)     // 100 / M2COEF

#define WS_NEEDED ((size_t)JC * NPTS * 8 * sizeof(float))  // 16.78 MB

typedef float v2f __attribute__((ext_vector_type(2)));

__device__ __forceinline__ v2f vsplat(float s) { v2f r; r.x = s; r.y = s; return r; }

__device__ __forceinline__ v2f pkfma(v2f a, v2f b, v2f c) {
#if __has_builtin(__builtin_elementwise_fma)
    return __builtin_elementwise_fma(a, b, c);
#else
    v2f r; r.x = fmaf(a.x, b.x, c.x); r.y = fmaf(a.y, b.y, c.y); return r;
#endif
}

__device__ __forceinline__ float fast_exp2(float x) {
#if __has_builtin(__builtin_amdgcn_exp2f)
    return __builtin_amdgcn_exp2f(x);
#else
    return exp2f(x);
#endif
}

__device__ __forceinline__ float clamp1(float v) {
    return fminf(fmaxf(v, -1.0f), 1.0f);
}

// ws layout: ws[((c*NPTS)+i)*8 + k], k=0..3: dcp0,dcp1,dcp2,wsum
//                                    k=4..7: wxs0,wxs1,wxs2,0 (wxs = M2COEF*wx)
__global__ __launch_bounds__(BI, 4) void lddmm_partial(const float* __restrict__ mom,
                                                       const float* __restrict__ cp,
                                                       float* __restrict__ ws) {
    const int ib = (int)blockIdx.x / JC;
    const int jc = (int)blockIdx.x % JC;
    const int t  = (int)threadIdx.x;
    const int i0 = ib * (BI * 2) + t;     // component .x
    const int i1 = i0 + BI;               // component .y

    // i-side data packed: {i0-value, i1-value}
    v2f xi0, xi1, xi2, ci, pi0, pi1, pi2;
    {
        const float a0 = cp[i0 * 3 + 0], a1 = cp[i0 * 3 + 1], a2 = cp[i0 * 3 + 2];
        const float b0 = cp[i1 * 3 + 0], b1 = cp[i1 * 3 + 1], b2 = cp[i1 * 3 + 2];
        xi0.x = a0; xi0.y = b0;
        xi1.x = a1; xi1.y = b1;
        xi2.x = a2; xi2.y = b2;
        ci.x = COEF * (a0 * a0 + a1 * a1 + a2 * a2);
        ci.y = COEF * (b0 * b0 + b1 * b1 + b2 * b2);
        pi0.x = clamp1(mom[i0 * 3 + 0]); pi0.y = clamp1(mom[i1 * 3 + 0]);
        pi1.x = clamp1(mom[i0 * 3 + 1]); pi1.y = clamp1(mom[i1 * 3 + 1]);
        pi2.x = clamp1(mom[i0 * 3 + 2]); pi2.y = clamp1(mom[i1 * 3 + 2]);
    }

    // Stage j-chunk: shx = {M2COEF*xj, COEF*|xj|^2}, shp = {pj clamped, 0}
    __shared__ float4 shx[JLEN];
    __shared__ float4 shp[JLEN];
    if (t < JLEN) {
        const int j = jc * JLEN + t;
        const float x0 = cp[j * 3 + 0], x1 = cp[j * 3 + 1], x2 = cp[j * 3 + 2];
        shx[t] = make_float4(M2COEF * x0, M2COEF * x1, M2COEF * x2,
                             COEF * (x0 * x0 + x1 * x1 + x2 * x2));
        shp[t] = make_float4(clamp1(mom[j * 3 + 0]), clamp1(mom[j * 3 + 1]),
                             clamp1(mom[j * 3 + 2]), 0.0f);
    }
    __syncthreads();

    v2f dcp0 = vsplat(0.f), dcp1 = vsplat(0.f), dcp2 = vsplat(0.f);
    v2f wsum = vsplat(0.f);
    v2f wx0 = vsplat(0.f), wx1 = vsplat(0.f), wx2 = vsplat(0.f);

#pragma unroll 8
    for (int jj = 0; jj < JLEN; ++jj) {
        const float4 xj = shx[jj];   // wave-uniform -> LDS broadcast
        const float4 pj = shp[jj];

        // arg = ci + cj + dot(xi, M2COEF*xj) = COEF*d2  (1 pk_add + 3 pk_fma)
        v2f arg = ci + vsplat(xj.w);
        arg = pkfma(xi2, vsplat(xj.z), arg);
        arg = pkfma(xi1, vsplat(xj.y), arg);
        arg = pkfma(xi0, vsplat(xj.x), arg);
        v2f K;                               // 2 trans
        K.x = fast_exp2(arg.x);
        K.y = fast_exp2(arg.y);
        v2f pd = pi0 * vsplat(pj.x);         // 1 pk_mul + 2 pk_fma
        pd = pkfma(pi1, vsplat(pj.y), pd);
        pd = pkfma(pi2, vsplat(pj.z), pd);
        const v2f W = K * pd;                // 1 pk_mul
        dcp0 = pkfma(K, vsplat(pj.x), dcp0); // 3 pk_fma
        dcp1 = pkfma(K, vsplat(pj.y), dcp1);
        dcp2 = pkfma(K, vsplat(pj.z), dcp2);
        wsum = wsum + W;                     // 1 pk_add
        wx0 = pkfma(W, vsplat(xj.x), wx0);   // 3 pk_fma (M2COEF-scaled)
        wx1 = pkfma(W, vsplat(xj.y), wx1);
        wx2 = pkfma(W, vsplat(xj.z), wx2);
    }

    float4* oa = (float4*)(ws + ((size_t)(jc * NPTS) + i0) * 8);
    oa[0] = make_float4(dcp0.x, dcp1.x, dcp2.x, wsum.x);
    oa[1] = make_float4(wx0.x, wx1.x, wx2.x, 0.0f);
    float4* ob = (float4*)(ws + ((size_t)(jc * NPTS) + i1) * 8);
    ob[0] = make_float4(dcp0.y, dcp1.y, dcp2.y, wsum.y);
    ob[1] = make_float4(wx0.y, wx1.y, wx2.y, 0.0f);
}

// 4 threads per i: sub=(cpart,half). Each sums JC/2 chunks of one float4,
// xor-2 combines chunk halves, xor-1 hands wsum from half0 to half1.
// dmom = 100*xi*wsum - (100/M2COEF)*wxs.
__global__ __launch_bounds__(256) void lddmm_reduce(const float* __restrict__ ws,
                                                    const float* __restrict__ cp,
                                                    float* __restrict__ out) {
    const int tid   = (int)blockIdx.x * 256 + (int)threadIdx.x;
    const int i     = tid >> 2;
    const int sub   = tid & 3;
    const int half  = sub & 1;
    const int cpart = sub >> 1;

    float4 acc = make_float4(0.f, 0.f, 0.f, 0.f);
    const int c0 = cpart * (JC / 2);
#pragma unroll 4
    for (int c = c0; c < c0 + JC / 2; ++c) {
        const float4 v = ((const float4*)(ws + ((size_t)(c * NPTS) + i) * 8))[half];
        acc.x += v.x; acc.y += v.y; acc.z += v.z; acc.w += v.w;
    }
    acc.x += __shfl_xor(acc.x, 2);
    acc.y += __shfl_xor(acc.y, 2);
    acc.z += __shfl_xor(acc.z, 2);
    acc.w += __shfl_xor(acc.w, 2);
    const float wsum = __shfl_xor(acc.w, 1);
    if (sub == 0) {
        out[N3 + i * 3 + 0] = acc.x;
        out[N3 + i * 3 + 1] = acc.y;
        out[N3 + i * 3 + 2] = acc.z;
    } else if (sub == 1) {
        const float xi0 = cp[i * 3 + 0];
        const float xi1 = cp[i * 3 + 1];
        const float xi2 = cp[i * 3 + 2];
        out[i * 3 + 0] = fmaf(100.0f * xi0, wsum, -UNSC100 * acc.x);
        out[i * 3 + 1] = fmaf(100.0f * xi1, wsum, -UNSC100 * acc.y);
        out[i * 3 + 2] = fmaf(100.0f * xi2, wsum, -UNSC100 * acc.z);
    }
}

// ---- fallback (atomics into d_out) if ws_size < WS_NEEDED ----
#define FJC   32
#define FJLEN (NPTS / FJC)
__global__ __launch_bounds__(BI) void lddmm_pairs_atomic(const float* __restrict__ mom,
                                                         const float* __restrict__ cp,
                                                         float* __restrict__ out) {
    const int ib = (int)blockIdx.x / FJC;
    const int jc = (int)blockIdx.x % FJC;
    const int t  = (int)threadIdx.x;
    const int i  = ib * BI + t;

    const float xi0 = cp[i * 3 + 0], xi1 = cp[i * 3 + 1], xi2 = cp[i * 3 + 2];
    const float pi0 = clamp1(mom[i * 3 + 0]), pi1 = clamp1(mom[i * 3 + 1]),
                pi2 = clamp1(mom[i * 3 + 2]);

    __shared__ float4 shx[FJLEN];
    __shared__ float4 shp[FJLEN];
    {
        const int j = jc * FJLEN + t;
        shx[t] = make_float4(cp[j * 3 + 0], cp[j * 3 + 1], cp[j * 3 + 2], 0.0f);
        shp[t] = make_float4(clamp1(mom[j * 3 + 0]), clamp1(mom[j * 3 + 1]),
                             clamp1(mom[j * 3 + 2]), 0.0f);
    }
    __syncthreads();

    float dcp0 = 0.f, dcp1 = 0.f, dcp2 = 0.f, wsum = 0.f, wx0 = 0.f, wx1 = 0.f, wx2 = 0.f;
#pragma unroll 4
    for (int jj = 0; jj < FJLEN; ++jj) {
        const float4 xj = shx[jj];
        const float4 pj = shp[jj];
        const float dx0 = xi0 - xj.x, dx1 = xi1 - xj.y, dx2 = xi2 - xj.z;
        const float d2  = dx0 * dx0 + dx1 * dx1 + dx2 * dx2;
        const float K   = fast_exp2(d2 * COEF);
        const float pd  = pi0 * pj.x + pi1 * pj.y + pi2 * pj.z;
        const float W   = K * pd;
        dcp0 += K * pj.x; dcp1 += K * pj.y; dcp2 += K * pj.z;
        wsum += W;
        wx0 += W * xj.x; wx1 += W * xj.y; wx2 += W * xj.z;
    }
    atomicAdd(&out[i * 3 + 0], 100.0f * (xi0 * wsum - wx0));
    atomicAdd(&out[i * 3 + 1], 100.0f * (xi1 * wsum - wx1));
    atomicAdd(&out[i * 3 + 2], 100.0f * (xi2 * wsum - wx2));
    atomicAdd(&out[N3 + i * 3 + 0], dcp0);
    atomicAdd(&out[N3 + i * 3 + 1], dcp1);
    atomicAdd(&out[N3 + i * 3 + 2], dcp2);
}

extern "C" void kernel_launch(void* const* d_in, const int* in_sizes, int n_in,
                              void* d_out, int out_size, void* d_ws, size_t ws_size,
                              hipStream_t stream) {
    const float* mom = (const float*)d_in[0];
    const float* cp  = (const float*)d_in[1];
    float* out = (float*)d_out;

    if (ws_size >= WS_NEEDED) {
        float* ws = (float*)d_ws;
        hipLaunchKernelGGL(lddmm_partial, dim3(IBLK * JC), dim3(BI), 0, stream, mom, cp, ws);
        hipLaunchKernelGGL(lddmm_reduce, dim3(NPTS * 4 / 256), dim3(256), 0, stream, ws, cp, out);
    } else {
        hipMemsetAsync(out, 0, (size_t)out_size * sizeof(float), stream);
        hipLaunchKernelGGL(lddmm_pairs_atomic, dim3((NPTS / BI) * FJC), dim3(BI), 0, stream, mom, cp, out);
    }
}